// Round 1
// baseline (1510.978 us; speedup 1.0000x reference)
//
#include <hip/hip_runtime.h>

#define NNODES 100000
#define INDIM 128
#define HID 256
#define NCLS 16
#define NGRAPH 64

// ---------------- CSR build ----------------
__global__ void hist_kernel(const int* __restrict__ dst, int* __restrict__ deg, int E) {
    int e = blockIdx.x * blockDim.x + threadIdx.x;
    if (e < E) atomicAdd(&deg[dst[e]], 1);
}

// single-block coarsened exclusive scan (n=100000, 1024 threads, ~98 elems/thread)
__global__ void scan_kernel(const int* __restrict__ deg, int* __restrict__ offs, int n) {
    __shared__ int sums[1024];
    int t = threadIdx.x;
    int per = (n + 1023) / 1024;
    int s = t * per, e = min(s + per, n);
    int sum = 0;
    for (int i = s; i < e; ++i) sum += deg[i];
    sums[t] = sum;
    __syncthreads();
    for (int off = 1; off < 1024; off <<= 1) {
        int v = (t >= off) ? sums[t - off] : 0;
        __syncthreads();
        sums[t] += v;
        __syncthreads();
    }
    int run = sums[t] - sum;  // exclusive prefix of this thread's chunk
    for (int i = s; i < e; ++i) { offs[i] = run; run += deg[i]; }
}

// uses offs as atomic cursor; afterwards offs[i] == end_i (start = end - deg)
__global__ void fill_kernel(const int* __restrict__ src, const int* __restrict__ dst,
                            int* offs, int* __restrict__ srclist, int E) {
    int e = blockIdx.x * blockDim.x + threadIdx.x;
    if (e < E) {
        int pos = atomicAdd(&offs[dst[e]], 1);
        srclist[pos] = src[e];
    }
}

// ---------------- mean aggregation: one wave per node ----------------
template <int FPL>  // floats per lane (2 -> 128-wide rows, 4 -> 256-wide rows)
__global__ void agg_kernel(const float* __restrict__ feat, const int* __restrict__ srclist,
                           const int* __restrict__ offs_end, const int* __restrict__ deg,
                           float* __restrict__ out, int n) {
    int gid = blockIdx.x * blockDim.x + threadIdx.x;
    int node = gid >> 6;
    int lane = gid & 63;
    if (node >= n) return;
    int end = offs_end[node];
    int d = deg[node];
    int start = end - d;
    float acc[FPL];
#pragma unroll
    for (int j = 0; j < FPL; ++j) acc[j] = 0.f;
    for (int e = start; e < end; ++e) {
        int s = srclist[e];
        const float* row = feat + (size_t)s * (64 * FPL) + lane * FPL;
        if (FPL == 2) {
            float2 v = *(const float2*)row;
            acc[0] += v.x; acc[1] += v.y;
        } else {
            float4 v = *(const float4*)row;
            acc[0] += v.x; acc[1] += v.y; acc[2] += v.z; acc[3] += v.w;
        }
    }
    float inv = 1.f / fmaxf((float)d, 1.f);
    float* orow = out + (size_t)node * (64 * FPL) + lane * FPL;
    if (FPL == 2) {
        *(float2*)orow = make_float2(acc[0] * inv, acc[1] * inv);
    } else {
        *(float4*)orow = make_float4(acc[0] * inv, acc[1] * inv, acc[2] * inv, acc[3] * inv);
    }
}

// ---------------- fused dual GEMM: H = relu(A1@B1 + A2@B2 + bias) ----------------
// A1,A2: [M x K] row-major. B1,B2: [K x 256] row-major. Tile: 32 rows x 256 cols.
// NOTE: H may alias A1 (in-place layer 2): each block reads only its own 32 A-rows,
// and all reads happen before the epilogue writes. No __restrict__ on A1/A2/H.
template <int K>
__global__ __launch_bounds__(256) void gemm_kernel(const float* A1, const float* A2,
                                                   const float* __restrict__ B1,
                                                   const float* __restrict__ B2,
                                                   const float* __restrict__ bias, float* H) {
    __shared__ float a_s[32][16];
    __shared__ float b_s[16][256];
    int t = threadIdx.x;
    int ct = t & 31;        // col thread: cols ct*8 .. ct*8+7
    int rt = t >> 5;        // row group: rows rt*4 .. rt*4+3
    int r0 = blockIdx.x * 32;

    float acc[4][8];
#pragma unroll
    for (int i = 0; i < 4; ++i)
#pragma unroll
        for (int j = 0; j < 8; ++j) acc[i][j] = 0.f;

    float breg[8];
#pragma unroll
    for (int j = 0; j < 8; ++j) breg[j] = bias[ct * 8 + j];

    const int NCH = (2 * K) / 16;
    for (int c = 0; c < NCH; ++c) {
        int kg = c * 16;
        const float* A = (kg < K) ? A1 : A2;
        const float* B = (kg < K) ? B1 : B2;
        int kk = (kg < K) ? kg : kg - K;
        __syncthreads();
        {   // stage A chunk: 32 rows x 16 k (float2 per thread)
            int ar = t >> 3, ak = (t & 7) * 2;
            float2 v = *(const float2*)(A + (size_t)(r0 + ar) * K + kk + ak);
            a_s[ar][ak] = v.x;
            a_s[ar][ak + 1] = v.y;
        }
        {   // stage B chunk: 16 k x 256 cols (4x float4 per thread)
            int kb = t >> 4, cb = (t & 15) * 16;
            const float4* bp = (const float4*)(B + (size_t)(kk + kb) * 256 + cb);
            float4 v0 = bp[0], v1 = bp[1], v2 = bp[2], v3 = bp[3];
            float4* sp = (float4*)&b_s[kb][cb];
            sp[0] = v0; sp[1] = v1; sp[2] = v2; sp[3] = v3;
        }
        __syncthreads();
#pragma unroll
        for (int k = 0; k < 16; ++k) {
            float a[4];
#pragma unroll
            for (int i = 0; i < 4; ++i) a[i] = a_s[rt * 4 + i][k];
            float4 bv0 = *(float4*)&b_s[k][ct * 8];
            float4 bv1 = *(float4*)&b_s[k][ct * 8 + 4];
            float b[8] = {bv0.x, bv0.y, bv0.z, bv0.w, bv1.x, bv1.y, bv1.z, bv1.w};
#pragma unroll
            for (int i = 0; i < 4; ++i)
#pragma unroll
                for (int j = 0; j < 8; ++j) acc[i][j] += a[i] * b[j];
        }
    }
    // epilogue: bias + relu, coalesced float4 stores
#pragma unroll
    for (int i = 0; i < 4; ++i) {
        int row = r0 + rt * 4 + i;
        float* hp = H + (size_t)row * 256 + ct * 8;
        float4 o0 = make_float4(fmaxf(acc[i][0] + breg[0], 0.f), fmaxf(acc[i][1] + breg[1], 0.f),
                                fmaxf(acc[i][2] + breg[2], 0.f), fmaxf(acc[i][3] + breg[3], 0.f));
        float4 o1 = make_float4(fmaxf(acc[i][4] + breg[4], 0.f), fmaxf(acc[i][5] + breg[5], 0.f),
                                fmaxf(acc[i][6] + breg[6], 0.f), fmaxf(acc[i][7] + breg[7], 0.f));
        *(float4*)hp = o0;
        *((float4*)hp + 1) = o1;
    }
}

// ---------------- segmented mean pool (batch sorted) ----------------
__global__ void pool_kernel(const float* __restrict__ h2, const int* __restrict__ batch,
                            float* __restrict__ g, float* __restrict__ cnt, int n) {
    int col = threadIdx.x;  // 256 cols
    int row0 = blockIdx.x * 256;
    float acc = 0.f;
    int cur = -1, seglen = 0;
    for (int r = 0; r < 256; ++r) {
        int row = row0 + r;
        if (row >= n) break;
        int b = batch[row];
        if (b != cur) {
            if (cur >= 0) {
                atomicAdd(&g[cur * 256 + col], acc);
                if (col == 0) atomicAdd(&cnt[cur], (float)seglen);
            }
            acc = 0.f;
            cur = b;
            seglen = 0;
        }
        acc += h2[(size_t)row * 256 + col];
        seglen++;
    }
    if (cur >= 0) {
        atomicAdd(&g[cur * 256 + col], acc);
        if (col == 0) atomicAdd(&cnt[cur], (float)seglen);
    }
}

// ---------------- classifier: out[64x16] = (g/cnt) @ fcW + fcb ----------------
__global__ void final_kernel(const float* __restrict__ g, const float* __restrict__ cnt,
                             const float* __restrict__ fcW, const float* __restrict__ fcb,
                             float* __restrict__ out) {
    int t = threadIdx.x;
    for (int o = t; o < NGRAPH * NCLS; o += 256) {
        int gi = o >> 4, c = o & 15;
        float inv = 1.f / fmaxf(cnt[gi], 1.f);
        float dot = 0.f;
        for (int k = 0; k < 256; ++k) dot += g[gi * 256 + k] * fcW[k * 16 + c];
        out[o] = dot * inv + fcb[c];
    }
}

extern "C" void kernel_launch(void* const* d_in, const int* in_sizes, int n_in, void* d_out,
                              int out_size, void* d_ws, size_t ws_size, hipStream_t stream) {
    const float* x   = (const float*)d_in[0];
    const int* edge  = (const int*)d_in[1];
    const int* batch = (const int*)d_in[2];
    const float* W1l = (const float*)d_in[3];
    const float* b1  = (const float*)d_in[4];
    const float* W1r = (const float*)d_in[5];
    const float* W2l = (const float*)d_in[6];
    const float* b2  = (const float*)d_in[7];
    const float* W2r = (const float*)d_in[8];
    const float* fcW = (const float*)d_in[9];
    const float* fcb = (const float*)d_in[10];
    float* out = (float*)d_out;

    const int n = in_sizes[0] / INDIM;   // 100000
    const int E = in_sizes[1] / 2;       // 1600000
    const int* src = edge;
    const int* dst = edge + E;

    // workspace layout (512-aligned), ~202 MiB total
    char* ws = (char*)d_ws;
    size_t off = 0;
    auto alloc = [&](size_t bytes) {
        size_t p = off;
        off = (off + bytes + 511) & ~(size_t)511;
        return p;
    };
    size_t offs_o    = alloc((size_t)n * 4);
    size_t deg_o     = alloc((size_t)n * 4);      // zeroed
    size_t cnt_o     = alloc(64 * 4);             // zeroed
    size_t g_o       = alloc(64 * 256 * 4);       // zeroed
    size_t zero_end  = off;
    size_t srclist_o = alloc((size_t)E * 4);
    size_t bufA_o    = alloc((size_t)n * 256 * 4);  // mean1 (first half), then mean2/h2 in place
    size_t h1_o      = alloc((size_t)n * 256 * 4);

    int*   offs    = (int*)(ws + offs_o);
    int*   deg     = (int*)(ws + deg_o);
    float* cnt     = (float*)(ws + cnt_o);
    float* g       = (float*)(ws + g_o);
    int*   srclist = (int*)(ws + srclist_o);
    float* bufA    = (float*)(ws + bufA_o);
    float* h1      = (float*)(ws + h1_o);

    hipMemsetAsync(ws + deg_o, 0, zero_end - deg_o, stream);

    int eb = (E + 255) / 256;
    hist_kernel<<<eb, 256, 0, stream>>>(dst, deg, E);
    scan_kernel<<<1, 1024, 0, stream>>>(deg, offs, n);
    fill_kernel<<<eb, 256, 0, stream>>>(src, dst, offs, srclist, E);

    int aggb = (n * 64 + 255) / 256;
    // layer 1: mean of x -> bufA (as mean1, 128-wide)
    agg_kernel<2><<<aggb, 256, 0, stream>>>(x, srclist, offs, deg, bufA, n);
    // h1 = relu(mean1@W1l + x@W1r + b1)
    gemm_kernel<128><<<n / 32, 256, 0, stream>>>(bufA, x, W1l, W1r, b1, h1);
    // layer 2: mean of h1 -> bufA (mean2, 256-wide)
    agg_kernel<4><<<aggb, 256, 0, stream>>>(h1, srclist, offs, deg, bufA, n);
    // h2 = relu(mean2@W2l + h1@W2r + b2), in place over bufA
    gemm_kernel<256><<<n / 32, 256, 0, stream>>>(bufA, h1, W2l, W2r, b2, bufA);

    pool_kernel<<<(n + 255) / 256, 256, 0, stream>>>(bufA, batch, g, cnt, n);
    final_kernel<<<1, 256, 0, stream>>>(g, cnt, fcW, fcb, out);
}

// Round 2
// 977.495 us; speedup vs baseline: 1.5458x; 1.5458x over previous
//
#include <hip/hip_runtime.h>

#define INDIM 128
#define HID 256
#define NCLS 16
#define NGRAPH 64

typedef __bf16 bf16_t;
typedef bf16_t bf16x8 __attribute__((ext_vector_type(8)));
typedef float f32x4 __attribute__((ext_vector_type(4)));

__device__ __forceinline__ float bfu_lo(unsigned v) {  // low ushort -> float
    union { unsigned i; float f; } u; u.i = v << 16; return u.f;
}
__device__ __forceinline__ float bfu_hi(unsigned v) {  // high ushort -> float
    union { unsigned i; float f; } u; u.i = v & 0xffff0000u; return u.f;
}
__device__ __forceinline__ unsigned short f2bf(float f) {  // RNE
    union { float f; unsigned i; } u; u.f = f;
    unsigned b = u.i;
    return (unsigned short)((b + 0x7fffu + ((b >> 16) & 1u)) >> 16);
}

// ---------------- CSR build ----------------
__global__ void hist_kernel(const int* __restrict__ dst, int* __restrict__ deg, int E) {
    int e = blockIdx.x * blockDim.x + threadIdx.x;
    if (e < E) atomicAdd(&deg[dst[e]], 1);
}

__global__ void scan_kernel(const int* __restrict__ deg, int* __restrict__ offs, int n) {
    __shared__ int sums[1024];
    int t = threadIdx.x;
    int per = (n + 1023) / 1024;
    int s = t * per, e = min(s + per, n);
    int sum = 0;
    for (int i = s; i < e; ++i) sum += deg[i];
    sums[t] = sum;
    __syncthreads();
    for (int off = 1; off < 1024; off <<= 1) {
        int v = (t >= off) ? sums[t - off] : 0;
        __syncthreads();
        sums[t] += v;
        __syncthreads();
    }
    int run = sums[t] - sum;
    for (int i = s; i < e; ++i) { offs[i] = run; run += deg[i]; }
}

__global__ void fill_kernel(const int* __restrict__ src, const int* __restrict__ dst,
                            int* offs, int* __restrict__ srclist, int E) {
    int e = blockIdx.x * blockDim.x + threadIdx.x;
    if (e < E) {
        int pos = atomicAdd(&offs[dst[e]], 1);
        srclist[pos] = src[e];
    }
}

// ---------------- casts ----------------
// x fp32 [M x 128] -> xb16 [M x 128] bf16 AND Acat1 cols 128..255 (row stride 256)
__global__ void cast_x_kernel(const float* __restrict__ x, unsigned short* __restrict__ xb,
                              unsigned short* __restrict__ acat1, int total4) {
    int idx = blockIdx.x * blockDim.x + threadIdx.x;
    if (idx >= total4) return;
    int i4 = idx * 4;
    float4 v = *(const float4*)(x + i4);
    ushort4 o = make_ushort4(f2bf(v.x), f2bf(v.y), f2bf(v.z), f2bf(v.w));
    *(ushort4*)(xb + i4) = o;
    int m = i4 >> 7, j = i4 & 127;
    *(ushort4*)(acat1 + (size_t)m * 256 + 128 + j) = o;
}

// Bt1[n*256 + k] = bf16( k<128 ? W1l[k][n] : W1r[k-128][n] )
__global__ void wcast1_kernel(const float* __restrict__ Wl, const float* __restrict__ Wr,
                              unsigned short* __restrict__ Bt) {
    int idx = blockIdx.x * blockDim.x + threadIdx.x;  // 65536
    int n = idx >> 8, k = idx & 255;
    float v = (k < 128) ? Wl[(size_t)k * 256 + n] : Wr[(size_t)(k - 128) * 256 + n];
    Bt[(size_t)n * 256 + k] = f2bf(v);
}

// Bt2[n*512 + k] = bf16( k<256 ? W2l[k][n] : W2r[k-256][n] )
__global__ void wcast2_kernel(const float* __restrict__ Wl, const float* __restrict__ Wr,
                              unsigned short* __restrict__ Bt) {
    int idx = blockIdx.x * blockDim.x + threadIdx.x;  // 131072
    int n = idx >> 9, k = idx & 511;
    float v = (k < 256) ? Wl[(size_t)k * 256 + n] : Wr[(size_t)(k - 256) * 256 + n];
    Bt[(size_t)n * 512 + k] = f2bf(v);
}

// ---------------- mean aggregation (bf16 gather, fp32 acc) ----------------
// layer1: rows 128 wide; write into acat (stride 256) cols lane*2
__global__ void agg1_kernel(const unsigned short* __restrict__ xb, const int* __restrict__ srclist,
                            const int* __restrict__ offs_end, const int* __restrict__ deg,
                            unsigned short* __restrict__ acat, int n) {
    int gid = blockIdx.x * blockDim.x + threadIdx.x;
    int node = gid >> 6, lane = gid & 63;
    if (node >= n) return;
    int end = offs_end[node], d = deg[node], st = end - d;
    float a0 = 0.f, a1 = 0.f, b0 = 0.f, b1 = 0.f;
    int e = st;
    for (; e + 1 < end; e += 2) {
        int s0 = srclist[e], s1 = srclist[e + 1];
        unsigned v0 = *(const unsigned*)(xb + (size_t)s0 * 128 + lane * 2);
        unsigned v1 = *(const unsigned*)(xb + (size_t)s1 * 128 + lane * 2);
        a0 += bfu_lo(v0); a1 += bfu_hi(v0);
        b0 += bfu_lo(v1); b1 += bfu_hi(v1);
    }
    if (e < end) {
        unsigned v0 = *(const unsigned*)(xb + (size_t)srclist[e] * 128 + lane * 2);
        a0 += bfu_lo(v0); a1 += bfu_hi(v0);
    }
    float inv = 1.f / fmaxf((float)d, 1.f);
    ushort2 o = make_ushort2(f2bf((a0 + b0) * inv), f2bf((a1 + b1) * inv));
    *(ushort2*)(acat + (size_t)node * 256 + lane * 2) = o;
}

// layer2: rows 256 wide; write into acat2 (stride 512) cols lane*4
__global__ void agg2_kernel(const unsigned short* __restrict__ h1, const int* __restrict__ srclist,
                            const int* __restrict__ offs_end, const int* __restrict__ deg,
                            unsigned short* __restrict__ acat, int n) {
    int gid = blockIdx.x * blockDim.x + threadIdx.x;
    int node = gid >> 6, lane = gid & 63;
    if (node >= n) return;
    int end = offs_end[node], d = deg[node], st = end - d;
    float a0 = 0.f, a1 = 0.f, a2 = 0.f, a3 = 0.f;
    float b0 = 0.f, b1 = 0.f, b2 = 0.f, b3 = 0.f;
    int e = st;
    for (; e + 1 < end; e += 2) {
        int s0 = srclist[e], s1 = srclist[e + 1];
        uint2 v0 = *(const uint2*)(h1 + (size_t)s0 * 256 + lane * 4);
        uint2 v1 = *(const uint2*)(h1 + (size_t)s1 * 256 + lane * 4);
        a0 += bfu_lo(v0.x); a1 += bfu_hi(v0.x); a2 += bfu_lo(v0.y); a3 += bfu_hi(v0.y);
        b0 += bfu_lo(v1.x); b1 += bfu_hi(v1.x); b2 += bfu_lo(v1.y); b3 += bfu_hi(v1.y);
    }
    if (e < end) {
        uint2 v0 = *(const uint2*)(h1 + (size_t)srclist[e] * 256 + lane * 4);
        a0 += bfu_lo(v0.x); a1 += bfu_hi(v0.x); a2 += bfu_lo(v0.y); a3 += bfu_hi(v0.y);
    }
    float inv = 1.f / fmaxf((float)d, 1.f);
    ushort4 o = make_ushort4(f2bf((a0 + b0) * inv), f2bf((a1 + b1) * inv),
                             f2bf((a2 + b2) * inv), f2bf((a3 + b3) * inv));
    *(ushort4*)(acat + (size_t)node * 512 + lane * 4) = o;
}

// ---------------- MFMA GEMM: H = relu(A @ B + bias), A [M x K] bf16, Bt [256 x K] bf16 ----------------
// Block: 256 threads = 4 waves. Block tile: 64 rows x 256 cols; wave w = cols w*64..w*64+63.
// No LDS: A/B fragments load straight from global (weights L1/L2-resident; A rows shared via L1).
// mfma_f32_16x16x32_bf16 layouts (HW-verified per guide):
//   A-frag: lane holds A[m=lane&15][k=quad*8+j]  (16B contiguous when A is k-contiguous)
//   B-frag: lane holds B[k=quad*8+j][n=lane&15]  -> read from Bt[n][k] (k-contiguous)
//   C/D:    row = quad*4 + reg, col = lane&15
template <int K>
__global__ __launch_bounds__(256) void mfma_gemm_kernel(
        const bf16_t* __restrict__ A, const bf16_t* __restrict__ Bt,
        const float* __restrict__ bias,
        unsigned short* __restrict__ H1,        // [M x 256] bf16
        unsigned short* __restrict__ H2,        // optional: [M x 512], written at col+256 (or null)
        int M) {
    int t = threadIdx.x;
    int wave = t >> 6, lane = t & 63;
    int quad = lane >> 4, l16 = lane & 15;
    int row0 = blockIdx.x * 64;
    int n0 = wave * 64;

    f32x4 acc[4][4];
#pragma unroll
    for (int i = 0; i < 4; ++i)
#pragma unroll
        for (int j = 0; j < 4; ++j) acc[i][j] = (f32x4)(0.f);

    const bf16_t* Ap = A + (size_t)(row0 + l16) * K + quad * 8;
    const bf16_t* Bp = Bt + (size_t)(n0 + l16) * K + quad * 8;

#pragma unroll 4
    for (int k0 = 0; k0 < K; k0 += 32) {
        bf16x8 af[4], bf[4];
#pragma unroll
        for (int mi = 0; mi < 4; ++mi)
            af[mi] = *(const bf16x8*)(Ap + (size_t)mi * 16 * K + k0);
#pragma unroll
        for (int ni = 0; ni < 4; ++ni)
            bf[ni] = *(const bf16x8*)(Bp + (size_t)ni * 16 * K + k0);
#pragma unroll
        for (int mi = 0; mi < 4; ++mi)
#pragma unroll
            for (int ni = 0; ni < 4; ++ni)
                acc[mi][ni] = __builtin_amdgcn_mfma_f32_16x16x32_bf16(af[mi], bf[ni], acc[mi][ni], 0, 0, 0);
    }

    float bv[4];
#pragma unroll
    for (int ni = 0; ni < 4; ++ni) bv[ni] = bias[n0 + ni * 16 + l16];

#pragma unroll
    for (int mi = 0; mi < 4; ++mi) {
#pragma unroll
        for (int r = 0; r < 4; ++r) {
            int row = row0 + mi * 16 + quad * 4 + r;
            if (row < M) {
#pragma unroll
                for (int ni = 0; ni < 4; ++ni) {
                    int col = n0 + ni * 16 + l16;
                    unsigned short hv = f2bf(fmaxf(acc[mi][ni][r] + bv[ni], 0.f));
                    H1[(size_t)row * 256 + col] = hv;
                    if (H2) H2[(size_t)row * 512 + 256 + col] = hv;
                }
            }
        }
    }
}

// ---------------- segmented mean pool (batch sorted), bf16 in / fp32 atomics out ----------------
__global__ void pool_kernel(const unsigned short* __restrict__ h2, const int* __restrict__ batch,
                            float* __restrict__ g, float* __restrict__ cnt, int n) {
    int col = threadIdx.x;  // 256 cols
    int row0 = blockIdx.x * 256;
    float acc = 0.f;
    int cur = -1, seglen = 0;
    for (int r = 0; r < 256; ++r) {
        int row = row0 + r;
        if (row >= n) break;
        int b = batch[row];
        if (b != cur) {
            if (cur >= 0) {
                atomicAdd(&g[cur * 256 + col], acc);
                if (col == 0) atomicAdd(&cnt[cur], (float)seglen);
            }
            acc = 0.f; cur = b; seglen = 0;
        }
        union { unsigned i; float f; } u;
        u.i = ((unsigned)h2[(size_t)row * 256 + col]) << 16;
        acc += u.f;
        seglen++;
    }
    if (cur >= 0) {
        atomicAdd(&g[cur * 256 + col], acc);
        if (col == 0) atomicAdd(&cnt[cur], (float)seglen);
    }
}

// ---------------- classifier ----------------
__global__ void final_kernel(const float* __restrict__ g, const float* __restrict__ cnt,
                             const float* __restrict__ fcW, const float* __restrict__ fcb,
                             float* __restrict__ out) {
    int t = threadIdx.x;
    for (int o = t; o < NGRAPH * NCLS; o += 256) {
        int gi = o >> 4, c = o & 15;
        float inv = 1.f / fmaxf(cnt[gi], 1.f);
        float dot = 0.f;
        for (int k = 0; k < 256; ++k) dot += g[gi * 256 + k] * fcW[k * 16 + c];
        out[o] = dot * inv + fcb[c];
    }
}

extern "C" void kernel_launch(void* const* d_in, const int* in_sizes, int n_in, void* d_out,
                              int out_size, void* d_ws, size_t ws_size, hipStream_t stream) {
    const float* x   = (const float*)d_in[0];
    const int* edge  = (const int*)d_in[1];
    const int* batch = (const int*)d_in[2];
    const float* W1l = (const float*)d_in[3];
    const float* b1  = (const float*)d_in[4];
    const float* W1r = (const float*)d_in[5];
    const float* W2l = (const float*)d_in[6];
    const float* b2  = (const float*)d_in[7];
    const float* W2r = (const float*)d_in[8];
    const float* fcW = (const float*)d_in[9];
    const float* fcb = (const float*)d_in[10];
    float* out = (float*)d_out;

    const int n = in_sizes[0] / INDIM;   // 100000
    const int E = in_sizes[1] / 2;       // 1600000
    const int* src = edge;
    const int* dst = edge + E;

    // workspace layout (512-aligned), ~203 MiB total
    char* ws = (char*)d_ws;
    size_t off = 0;
    auto alloc = [&](size_t bytes) {
        size_t p = off;
        off = (off + bytes + 511) & ~(size_t)511;
        return p;
    };
    size_t offs_o    = alloc((size_t)n * 4);
    size_t deg_o     = alloc((size_t)n * 4);         // zeroed
    size_t cnt_o     = alloc(64 * 4);                // zeroed
    size_t g_o       = alloc(64 * 256 * 4);          // zeroed
    size_t zero_end  = off;
    size_t srclist_o = alloc((size_t)E * 4);
    size_t bt1_o     = alloc(256 * 256 * 2);
    size_t bt2_o     = alloc(256 * 512 * 2);
    size_t acat2_o   = alloc((size_t)n * 512 * 2);   // first n*128*2 doubles as xb16 (dead before acat2 writes)
    size_t acat1_o   = alloc((size_t)n * 256 * 2);
    size_t h1_o      = alloc((size_t)n * 256 * 2);   // h1b, then h2b in place (gemm2 never reads h1b)

    int*   offs    = (int*)(ws + offs_o);
    int*   deg     = (int*)(ws + deg_o);
    float* cnt     = (float*)(ws + cnt_o);
    float* g       = (float*)(ws + g_o);
    int*   srclist = (int*)(ws + srclist_o);
    unsigned short* Bt1   = (unsigned short*)(ws + bt1_o);
    unsigned short* Bt2   = (unsigned short*)(ws + bt2_o);
    unsigned short* acat2 = (unsigned short*)(ws + acat2_o);
    unsigned short* xb16  = (unsigned short*)(ws + acat2_o);   // alias: dead after agg1
    unsigned short* acat1 = (unsigned short*)(ws + acat1_o);
    unsigned short* h1b   = (unsigned short*)(ws + h1_o);
    unsigned short* h2b   = (unsigned short*)(ws + h1_o);      // alias: h1b dead after agg2

    hipMemsetAsync(ws + deg_o, 0, zero_end - deg_o, stream);

    int eb = (E + 255) / 256;
    hist_kernel<<<eb, 256, 0, stream>>>(dst, deg, E);
    scan_kernel<<<1, 1024, 0, stream>>>(deg, offs, n);
    fill_kernel<<<eb, 256, 0, stream>>>(src, dst, offs, srclist, E);

    cast_x_kernel<<<(n * INDIM / 4 + 255) / 256, 256, 0, stream>>>(x, xb16, acat1, n * INDIM / 4);
    wcast1_kernel<<<256, 256, 0, stream>>>(W1l, W1r, Bt1);
    wcast2_kernel<<<512, 256, 0, stream>>>(W2l, W2r, Bt2);

    int aggb = (n * 64 + 255) / 256;
    int gemmb = (n + 63) / 64;

    // layer 1
    agg1_kernel<<<aggb, 256, 0, stream>>>(xb16, srclist, offs, deg, acat1, n);
    mfma_gemm_kernel<256><<<gemmb, 256, 0, stream>>>(
        (const bf16_t*)acat1, (const bf16_t*)Bt1, b1, h1b, acat2, n);
    // layer 2
    agg2_kernel<<<aggb, 256, 0, stream>>>(h1b, srclist, offs, deg, acat2, n);
    mfma_gemm_kernel<512><<<gemmb, 256, 0, stream>>>(
        (const bf16_t*)acat2, (const bf16_t*)Bt2, b2, h2b, (unsigned short*)nullptr, n);

    pool_kernel<<<(n + 255) / 256, 256, 0, stream>>>(h2b, batch, g, cnt, n);
    final_kernel<<<1, 256, 0, stream>>>(g, cnt, fcW, fcb, out);
}

// Round 3
// 801.088 us; speedup vs baseline: 1.8862x; 1.2202x over previous
//
#include <hip/hip_runtime.h>

#define INDIM 128
#define HID 256
#define NCLS 16
#define NGRAPH 64

typedef __bf16 bf16_t;
typedef bf16_t bf16x8 __attribute__((ext_vector_type(8)));
typedef float f32x4 __attribute__((ext_vector_type(4)));

__device__ __forceinline__ float bfu_lo(unsigned v) {
    union { unsigned i; float f; } u; u.i = v << 16; return u.f;
}
__device__ __forceinline__ float bfu_hi(unsigned v) {
    union { unsigned i; float f; } u; u.i = v & 0xffff0000u; return u.f;
}
__device__ __forceinline__ unsigned short f2bf(float f) {  // RNE
    union { float f; unsigned i; } u; u.f = f;
    unsigned b = u.i;
    return (unsigned short)((b + 0x7fffu + ((b >> 16) & 1u)) >> 16);
}

// ---------------- CSR build ----------------
__global__ void hist_kernel(const int* __restrict__ dst, int* __restrict__ deg, int E) {
    int e = blockIdx.x * blockDim.x + threadIdx.x;
    if (e < E) atomicAdd(&deg[dst[e]], 1);
}

// hierarchical exclusive scan, 3 phases (was: 160us single-block serial scan)
__global__ void scan1_kernel(const int* __restrict__ deg, int* __restrict__ bsum, int n) {
    __shared__ int s[256];
    int t = threadIdx.x;
    int i = blockIdx.x * 256 + t;
    s[t] = (i < n) ? deg[i] : 0;
    __syncthreads();
    for (int off = 128; off > 0; off >>= 1) {
        if (t < off) s[t] += s[t + off];
        __syncthreads();
    }
    if (t == 0) bsum[blockIdx.x] = s[0];
}

__global__ void scan2_kernel(int* bsum, int nb) {  // single block, nb <= 1024
    __shared__ int s[1024];
    int t = threadIdx.x;
    int v = (t < nb) ? bsum[t] : 0;
    s[t] = v;
    __syncthreads();
    for (int off = 1; off < 1024; off <<= 1) {
        int u = (t >= off) ? s[t - off] : 0;
        __syncthreads();
        s[t] += u;
        __syncthreads();
    }
    if (t < nb) bsum[t] = s[t] - v;  // exclusive
}

__global__ void scan3_kernel(const int* __restrict__ deg, const int* __restrict__ bsum,
                             int* __restrict__ offs, int n) {
    __shared__ int s[256];
    int t = threadIdx.x;
    int i = blockIdx.x * 256 + t;
    int v = (i < n) ? deg[i] : 0;
    s[t] = v;
    __syncthreads();
    for (int off = 1; off < 256; off <<= 1) {
        int u = (t >= off) ? s[t - off] : 0;
        __syncthreads();
        s[t] += u;
        __syncthreads();
    }
    if (i < n) offs[i] = s[t] - v + bsum[blockIdx.x];
}

__global__ void fill_kernel(const int* __restrict__ src, const int* __restrict__ dst,
                            int* offs, int* __restrict__ srclist, int E) {
    int e = blockIdx.x * blockDim.x + threadIdx.x;
    if (e < E) {
        int pos = atomicAdd(&offs[dst[e]], 1);
        srclist[pos] = src[e];
    }
}

// ---------------- casts ----------------
__global__ void cast_x_kernel(const float* __restrict__ x, unsigned short* __restrict__ xb,
                              unsigned short* __restrict__ acat1, int total4) {
    int idx = blockIdx.x * blockDim.x + threadIdx.x;
    if (idx >= total4) return;
    int i4 = idx * 4;
    float4 v = *(const float4*)(x + i4);
    ushort4 o = make_ushort4(f2bf(v.x), f2bf(v.y), f2bf(v.z), f2bf(v.w));
    *(ushort4*)(xb + i4) = o;
    int m = i4 >> 7, j = i4 & 127;
    *(ushort4*)(acat1 + (size_t)m * 256 + 128 + j) = o;
}

__global__ void wcast1_kernel(const float* __restrict__ Wl, const float* __restrict__ Wr,
                              unsigned short* __restrict__ Bt) {
    int idx = blockIdx.x * blockDim.x + threadIdx.x;  // 65536
    int n = idx >> 8, k = idx & 255;
    float v = (k < 128) ? Wl[(size_t)k * 256 + n] : Wr[(size_t)(k - 128) * 256 + n];
    Bt[(size_t)n * 256 + k] = f2bf(v);
}

__global__ void wcast2_kernel(const float* __restrict__ Wl, const float* __restrict__ Wr,
                              unsigned short* __restrict__ Bt) {
    int idx = blockIdx.x * blockDim.x + threadIdx.x;  // 131072
    int n = idx >> 9, k = idx & 511;
    float v = (k < 256) ? Wl[(size_t)k * 256 + n] : Wr[(size_t)(k - 256) * 256 + n];
    Bt[(size_t)n * 512 + k] = f2bf(v);
}

// ---------------- mean aggregation (bf16 gather, fp32 acc, 4 indep chains) ----------------
__global__ void agg1_kernel(const unsigned short* __restrict__ xb, const int* __restrict__ srclist,
                            const int* __restrict__ offs_end, const int* __restrict__ deg,
                            unsigned short* __restrict__ acat, int n) {
    int gid = blockIdx.x * blockDim.x + threadIdx.x;
    int node = gid >> 6, lane = gid & 63;
    if (node >= n) return;
    int end = offs_end[node], d = deg[node], st = end - d;
    float a0 = 0.f, a1 = 0.f, b0 = 0.f, b1 = 0.f;
    float c0 = 0.f, c1 = 0.f, d0 = 0.f, d1 = 0.f;
    int e = st;
    for (; e + 3 < end; e += 4) {
        int s0 = srclist[e], s1 = srclist[e + 1], s2 = srclist[e + 2], s3 = srclist[e + 3];
        unsigned v0 = *(const unsigned*)(xb + (size_t)s0 * 128 + lane * 2);
        unsigned v1 = *(const unsigned*)(xb + (size_t)s1 * 128 + lane * 2);
        unsigned v2 = *(const unsigned*)(xb + (size_t)s2 * 128 + lane * 2);
        unsigned v3 = *(const unsigned*)(xb + (size_t)s3 * 128 + lane * 2);
        a0 += bfu_lo(v0); a1 += bfu_hi(v0);
        b0 += bfu_lo(v1); b1 += bfu_hi(v1);
        c0 += bfu_lo(v2); c1 += bfu_hi(v2);
        d0 += bfu_lo(v3); d1 += bfu_hi(v3);
    }
    for (; e < end; ++e) {
        unsigned v0 = *(const unsigned*)(xb + (size_t)srclist[e] * 128 + lane * 2);
        a0 += bfu_lo(v0); a1 += bfu_hi(v0);
    }
    float inv = 1.f / fmaxf((float)d, 1.f);
    ushort2 o = make_ushort2(f2bf(((a0 + b0) + (c0 + d0)) * inv),
                             f2bf(((a1 + b1) + (c1 + d1)) * inv));
    *(ushort2*)(acat + (size_t)node * 256 + lane * 2) = o;
}

__global__ void agg2_kernel(const unsigned short* __restrict__ h1, const int* __restrict__ srclist,
                            const int* __restrict__ offs_end, const int* __restrict__ deg,
                            unsigned short* __restrict__ acat, int n) {
    int gid = blockIdx.x * blockDim.x + threadIdx.x;
    int node = gid >> 6, lane = gid & 63;
    if (node >= n) return;
    int end = offs_end[node], d = deg[node], st = end - d;
    float a0 = 0, a1 = 0, a2 = 0, a3 = 0, b0 = 0, b1 = 0, b2 = 0, b3 = 0;
    float c0 = 0, c1 = 0, c2 = 0, c3 = 0, e0 = 0, e1 = 0, e2 = 0, e3 = 0;
    int e = st;
    for (; e + 3 < end; e += 4) {
        int s0 = srclist[e], s1 = srclist[e + 1], s2 = srclist[e + 2], s3 = srclist[e + 3];
        uint2 v0 = *(const uint2*)(h1 + (size_t)s0 * 256 + lane * 4);
        uint2 v1 = *(const uint2*)(h1 + (size_t)s1 * 256 + lane * 4);
        uint2 v2 = *(const uint2*)(h1 + (size_t)s2 * 256 + lane * 4);
        uint2 v3 = *(const uint2*)(h1 + (size_t)s3 * 256 + lane * 4);
        a0 += bfu_lo(v0.x); a1 += bfu_hi(v0.x); a2 += bfu_lo(v0.y); a3 += bfu_hi(v0.y);
        b0 += bfu_lo(v1.x); b1 += bfu_hi(v1.x); b2 += bfu_lo(v1.y); b3 += bfu_hi(v1.y);
        c0 += bfu_lo(v2.x); c1 += bfu_hi(v2.x); c2 += bfu_lo(v2.y); c3 += bfu_hi(v2.y);
        e0 += bfu_lo(v3.x); e1 += bfu_hi(v3.x); e2 += bfu_lo(v3.y); e3 += bfu_hi(v3.y);
    }
    for (; e < end; ++e) {
        uint2 v0 = *(const uint2*)(h1 + (size_t)srclist[e] * 256 + lane * 4);
        a0 += bfu_lo(v0.x); a1 += bfu_hi(v0.x); a2 += bfu_lo(v0.y); a3 += bfu_hi(v0.y);
    }
    float inv = 1.f / fmaxf((float)d, 1.f);
    ushort4 o = make_ushort4(f2bf(((a0 + b0) + (c0 + e0)) * inv),
                             f2bf(((a1 + b1) + (c1 + e1)) * inv),
                             f2bf(((a2 + b2) + (c2 + e2)) * inv),
                             f2bf(((a3 + b3) + (c3 + e3)) * inv));
    *(ushort4*)(acat + (size_t)node * 512 + lane * 4) = o;
}

// ---------------- MFMA GEMM (unchanged from R1; see R1 notes for layout proofs) ----------------
template <int K>
__global__ __launch_bounds__(256) void mfma_gemm_kernel(
        const bf16_t* __restrict__ A, const bf16_t* __restrict__ Bt,
        const float* __restrict__ bias,
        unsigned short* __restrict__ H1, unsigned short* __restrict__ H2, int M) {
    int t = threadIdx.x;
    int wave = t >> 6, lane = t & 63;
    int quad = lane >> 4, l16 = lane & 15;
    int row0 = blockIdx.x * 64;
    int n0 = wave * 64;

    f32x4 acc[4][4];
#pragma unroll
    for (int i = 0; i < 4; ++i)
#pragma unroll
        for (int j = 0; j < 4; ++j) acc[i][j] = (f32x4)(0.f);

    const bf16_t* Ap = A + (size_t)(row0 + l16) * K + quad * 8;
    const bf16_t* Bp = Bt + (size_t)(n0 + l16) * K + quad * 8;

#pragma unroll 4
    for (int k0 = 0; k0 < K; k0 += 32) {
        bf16x8 af[4], bf[4];
#pragma unroll
        for (int mi = 0; mi < 4; ++mi)
            af[mi] = *(const bf16x8*)(Ap + (size_t)mi * 16 * K + k0);
#pragma unroll
        for (int ni = 0; ni < 4; ++ni)
            bf[ni] = *(const bf16x8*)(Bp + (size_t)ni * 16 * K + k0);
#pragma unroll
        for (int mi = 0; mi < 4; ++mi)
#pragma unroll
            for (int ni = 0; ni < 4; ++ni)
                acc[mi][ni] = __builtin_amdgcn_mfma_f32_16x16x32_bf16(af[mi], bf[ni], acc[mi][ni], 0, 0, 0);
    }

    float bv[4];
#pragma unroll
    for (int ni = 0; ni < 4; ++ni) bv[ni] = bias[n0 + ni * 16 + l16];

#pragma unroll
    for (int mi = 0; mi < 4; ++mi) {
#pragma unroll
        for (int r = 0; r < 4; ++r) {
            int row = row0 + mi * 16 + quad * 4 + r;
            if (row < M) {
#pragma unroll
                for (int ni = 0; ni < 4; ++ni) {
                    int col = n0 + ni * 16 + l16;
                    unsigned short hv = f2bf(fmaxf(acc[mi][ni][r] + bv[ni], 0.f));
                    H1[(size_t)row * 256 + col] = hv;
                    if (H2) H2[(size_t)row * 512 + 256 + col] = hv;
                }
            }
        }
    }
}

// ---------------- segmented mean pool ----------------
__global__ void pool_kernel(const unsigned short* __restrict__ h2, const int* __restrict__ batch,
                            float* __restrict__ g, float* __restrict__ cnt, int n) {
    int col = threadIdx.x;
    int row0 = blockIdx.x * 256;
    float acc = 0.f;
    int cur = -1, seglen = 0;
    for (int r = 0; r < 256; ++r) {
        int row = row0 + r;
        if (row >= n) break;
        int b = batch[row];
        if (b != cur) {
            if (cur >= 0) {
                atomicAdd(&g[cur * 256 + col], acc);
                if (col == 0) atomicAdd(&cnt[cur], (float)seglen);
            }
            acc = 0.f; cur = b; seglen = 0;
        }
        union { unsigned i; float f; } u;
        u.i = ((unsigned)h2[(size_t)row * 256 + col]) << 16;
        acc += u.f;
        seglen++;
    }
    if (cur >= 0) {
        atomicAdd(&g[cur * 256 + col], acc);
        if (col == 0) atomicAdd(&cnt[cur], (float)seglen);
    }
}

// ---------------- classifier ----------------
__global__ void final_kernel(const float* __restrict__ g, const float* __restrict__ cnt,
                             const float* __restrict__ fcW, const float* __restrict__ fcb,
                             float* __restrict__ out) {
    int t = threadIdx.x;
    for (int o = t; o < NGRAPH * NCLS; o += 256) {
        int gi = o >> 4, c = o & 15;
        float inv = 1.f / fmaxf(cnt[gi], 1.f);
        float dot = 0.f;
        for (int k = 0; k < 256; ++k) dot += g[gi * 256 + k] * fcW[k * 16 + c];
        out[o] = dot * inv + fcb[c];
    }
}

extern "C" void kernel_launch(void* const* d_in, const int* in_sizes, int n_in, void* d_out,
                              int out_size, void* d_ws, size_t ws_size, hipStream_t stream) {
    const float* x   = (const float*)d_in[0];
    const int* edge  = (const int*)d_in[1];
    const int* batch = (const int*)d_in[2];
    const float* W1l = (const float*)d_in[3];
    const float* b1  = (const float*)d_in[4];
    const float* W1r = (const float*)d_in[5];
    const float* W2l = (const float*)d_in[6];
    const float* b2  = (const float*)d_in[7];
    const float* W2r = (const float*)d_in[8];
    const float* fcW = (const float*)d_in[9];
    const float* fcb = (const float*)d_in[10];
    float* out = (float*)d_out;

    const int n = in_sizes[0] / INDIM;   // 100000
    const int E = in_sizes[1] / 2;       // 1600000
    const int* src = edge;
    const int* dst = edge + E;

    char* ws = (char*)d_ws;
    size_t off = 0;
    auto alloc = [&](size_t bytes) {
        size_t p = off;
        off = (off + bytes + 511) & ~(size_t)511;
        return p;
    };
    size_t offs_o    = alloc((size_t)n * 4);
    size_t deg_o     = alloc((size_t)n * 4);         // zeroed
    size_t cnt_o     = alloc(64 * 4);                // zeroed
    size_t g_o       = alloc(64 * 256 * 4);          // zeroed
    size_t zero_end  = off;
    size_t bsum_o    = alloc(1024 * 4);
    size_t srclist_o = alloc((size_t)E * 4);
    size_t bt1_o     = alloc(256 * 256 * 2);
    size_t bt2_o     = alloc(256 * 512 * 2);
    size_t acat2_o   = alloc((size_t)n * 512 * 2);   // first n*128*2 doubles as xb16
    size_t acat1_o   = alloc((size_t)n * 256 * 2);
    size_t h1_o      = alloc((size_t)n * 256 * 2);   // h1b, then h2b in place

    int*   offs    = (int*)(ws + offs_o);
    int*   deg     = (int*)(ws + deg_o);
    float* cnt     = (float*)(ws + cnt_o);
    float* g       = (float*)(ws + g_o);
    int*   bsum    = (int*)(ws + bsum_o);
    int*   srclist = (int*)(ws + srclist_o);
    unsigned short* Bt1   = (unsigned short*)(ws + bt1_o);
    unsigned short* Bt2   = (unsigned short*)(ws + bt2_o);
    unsigned short* acat2 = (unsigned short*)(ws + acat2_o);
    unsigned short* xb16  = (unsigned short*)(ws + acat2_o);
    unsigned short* acat1 = (unsigned short*)(ws + acat1_o);
    unsigned short* h1b   = (unsigned short*)(ws + h1_o);
    unsigned short* h2b   = (unsigned short*)(ws + h1_o);

    hipMemsetAsync(ws + deg_o, 0, zero_end - deg_o, stream);

    int eb = (E + 255) / 256;
    int nb = (n + 255) / 256;  // 391
    hist_kernel<<<eb, 256, 0, stream>>>(dst, deg, E);
    scan1_kernel<<<nb, 256, 0, stream>>>(deg, bsum, n);
    scan2_kernel<<<1, 1024, 0, stream>>>(bsum, nb);
    scan3_kernel<<<nb, 256, 0, stream>>>(deg, bsum, offs, n);
    fill_kernel<<<eb, 256, 0, stream>>>(src, dst, offs, srclist, E);

    cast_x_kernel<<<(n * INDIM / 4 + 255) / 256, 256, 0, stream>>>(x, xb16, acat1, n * INDIM / 4);
    wcast1_kernel<<<256, 256, 0, stream>>>(W1l, W1r, Bt1);
    wcast2_kernel<<<512, 256, 0, stream>>>(W2l, W2r, Bt2);

    int aggb = (n * 64 + 255) / 256;
    int gemmb = (n + 63) / 64;

    agg1_kernel<<<aggb, 256, 0, stream>>>(xb16, srclist, offs, deg, acat1, n);
    mfma_gemm_kernel<256><<<gemmb, 256, 0, stream>>>(
        (const bf16_t*)acat1, (const bf16_t*)Bt1, b1, h1b, acat2, n);
    agg2_kernel<<<aggb, 256, 0, stream>>>(h1b, srclist, offs, deg, acat2, n);
    mfma_gemm_kernel<512><<<gemmb, 256, 0, stream>>>(
        (const bf16_t*)acat2, (const bf16_t*)Bt2, b2, h2b, (unsigned short*)nullptr, n);

    pool_kernel<<<nb, 256, 0, stream>>>(h2b, batch, g, cnt, n);
    final_kernel<<<1, 256, 0, stream>>>(g, cnt, fcW, fcb, out);
}

// Round 4
// 736.003 us; speedup vs baseline: 2.0529x; 1.0884x over previous
//
#include <hip/hip_runtime.h>

#define INDIM 128
#define HID 256
#define NCLS 16
#define NGRAPH 64
#define CHUNK 8192

typedef __bf16 bf16_t;
typedef bf16_t bf16x8 __attribute__((ext_vector_type(8)));
typedef float f32x4 __attribute__((ext_vector_type(4)));

__device__ __forceinline__ float bfu_lo(unsigned v) {
    union { unsigned i; float f; } u; u.i = v << 16; return u.f;
}
__device__ __forceinline__ float bfu_hi(unsigned v) {
    union { unsigned i; float f; } u; u.i = v & 0xffff0000u; return u.f;
}
__device__ __forceinline__ unsigned short f2bf(float f) {  // RNE
    union { float f; unsigned i; } u; u.f = f;
    unsigned b = u.i;
    return (unsigned short)((b + 0x7fffu + ((b >> 16) & 1u)) >> 16);
}

// ---------------- CSR build ----------------
__global__ void hist_kernel(const int* __restrict__ dst, int* __restrict__ deg, int E) {
    int e = blockIdx.x * blockDim.x + threadIdx.x;
    if (e < E) atomicAdd(&deg[dst[e]], 1);
}

__global__ void scan1_kernel(const int* __restrict__ deg, int* __restrict__ bsum, int n) {
    __shared__ int s[256];
    int t = threadIdx.x;
    int i = blockIdx.x * 256 + t;
    s[t] = (i < n) ? deg[i] : 0;
    __syncthreads();
    for (int off = 128; off > 0; off >>= 1) {
        if (t < off) s[t] += s[t + off];
        __syncthreads();
    }
    if (t == 0) bsum[blockIdx.x] = s[0];
}

__global__ void scan2_kernel(int* bsum, int nb) {  // single block, nb <= 1024
    __shared__ int s[1024];
    int t = threadIdx.x;
    int v = (t < nb) ? bsum[t] : 0;
    s[t] = v;
    __syncthreads();
    for (int off = 1; off < 1024; off <<= 1) {
        int u = (t >= off) ? s[t - off] : 0;
        __syncthreads();
        s[t] += u;
        __syncthreads();
    }
    if (t < nb) bsum[t] = s[t] - v;  // exclusive
}

__global__ void scan3_kernel(const int* __restrict__ deg, const int* __restrict__ bsum,
                             int* __restrict__ offs, int n) {
    __shared__ int s[256];
    int t = threadIdx.x;
    int i = blockIdx.x * 256 + t;
    int v = (i < n) ? deg[i] : 0;
    s[t] = v;
    __syncthreads();
    for (int off = 1; off < 256; off <<= 1) {
        int u = (t >= off) ? s[t - off] : 0;
        __syncthreads();
        s[t] += u;
        __syncthreads();
    }
    if (i < n) offs[i] = s[t] - v + bsum[blockIdx.x];
}

// ---------------- two-phase locality-aware edge sort (replaces fill_kernel) ----------------
// Old fill: random 4B scatters -> 105 MB writeback (16x amp, cross-XCD line ping-pong).
// Phase A: bucket edges by dst>>8; per-block LDS histogram + one global atomic per
// (block,bucket) reserves a CONTIGUOUS run -> ~1.4x write amp on 6.4 MB payload.
__global__ void initcur_kernel(const int* __restrict__ offs, int* __restrict__ gcur, int nbuck) {
    int t = blockIdx.x * blockDim.x + threadIdx.x;
    if (t < nbuck) gcur[t] = offs[t << 8];
}

__global__ __launch_bounds__(256) void binA_kernel(const int* __restrict__ src,
                                                   const int* __restrict__ dst,
                                                   int* __restrict__ gcur,
                                                   unsigned* __restrict__ tmp,
                                                   int E, int nbuck) {
    __shared__ int hist[512];
    __shared__ int base[512];
    int t = threadIdx.x;
    int e0 = blockIdx.x * CHUNK;
    int e1 = min(e0 + CHUNK, E);
    for (int i = t; i < nbuck; i += 256) hist[i] = 0;
    __syncthreads();
    for (int e = e0 + t; e < e1; e += 256) atomicAdd(&hist[dst[e] >> 8], 1);
    __syncthreads();
    for (int i = t; i < nbuck; i += 256) {
        int c = hist[i];
        base[i] = (c > 0) ? atomicAdd(&gcur[i], c) : 0;
    }
    __syncthreads();
    for (int e = e0 + t; e < e1; e += 256) {
        int d = dst[e];
        int p = atomicAdd(&base[d >> 8], 1);
        tmp[p] = ((unsigned)(d & 255) << 17) | (unsigned)src[e];  // src < 2^17
    }
}

// Phase B: one block per bucket; per-node cursors in LDS; scatter hits a ~16 KB
// block-local region -> lines fill in one CU's L1 -> full-line writebacks (6.4 MB).
__global__ __launch_bounds__(256) void binB_kernel(const unsigned* __restrict__ tmp,
                                                   const int* __restrict__ offs,
                                                   int* __restrict__ srclist, int E, int n) {
    __shared__ int cur[256];
    int b = blockIdx.x;
    int node0 = b << 8;
    int nnodes = min(256, n - node0);
    int t = threadIdx.x;
    if (t < nnodes) cur[t] = offs[node0 + t];
    __syncthreads();
    int ebeg = offs[node0];
    int eend = (node0 + 256 < n) ? offs[node0 + 256] : E;
    for (int e = ebeg + t; e < eend; e += 256) {
        unsigned v = tmp[e];
        int p = atomicAdd(&cur[v >> 17], 1);
        srclist[p] = (int)(v & 0x1FFFFu);
    }
}

// ---------------- casts ----------------
__global__ void cast_x_kernel(const float* __restrict__ x, unsigned short* __restrict__ xb,
                              unsigned short* __restrict__ acat1, int total4) {
    int idx = blockIdx.x * blockDim.x + threadIdx.x;
    if (idx >= total4) return;
    int i4 = idx * 4;
    float4 v = *(const float4*)(x + i4);
    ushort4 o = make_ushort4(f2bf(v.x), f2bf(v.y), f2bf(v.z), f2bf(v.w));
    *(ushort4*)(xb + i4) = o;
    int m = i4 >> 7, j = i4 & 127;
    *(ushort4*)(acat1 + (size_t)m * 256 + 128 + j) = o;
}

__global__ void wcast1_kernel(const float* __restrict__ Wl, const float* __restrict__ Wr,
                              unsigned short* __restrict__ Bt) {
    int idx = blockIdx.x * blockDim.x + threadIdx.x;  // 65536
    int n = idx >> 8, k = idx & 255;
    float v = (k < 128) ? Wl[(size_t)k * 256 + n] : Wr[(size_t)(k - 128) * 256 + n];
    Bt[(size_t)n * 256 + k] = f2bf(v);
}

__global__ void wcast2_kernel(const float* __restrict__ Wl, const float* __restrict__ Wr,
                              unsigned short* __restrict__ Bt) {
    int idx = blockIdx.x * blockDim.x + threadIdx.x;  // 131072
    int n = idx >> 9, k = idx & 511;
    float v = (k < 256) ? Wl[(size_t)k * 256 + n] : Wr[(size_t)(k - 256) * 256 + n];
    Bt[(size_t)n * 512 + k] = f2bf(v);
}

// ---------------- mean aggregation (bf16 gather, fp32 acc, 4 indep chains) ----------------
// NOTE: offs now holds segment STARTS (pristine scan output); end = start + deg.
__global__ void agg1_kernel(const unsigned short* __restrict__ xb, const int* __restrict__ srclist,
                            const int* __restrict__ offs, const int* __restrict__ deg,
                            unsigned short* __restrict__ acat, int n) {
    int gid = blockIdx.x * blockDim.x + threadIdx.x;
    int node = gid >> 6, lane = gid & 63;
    if (node >= n) return;
    int st = offs[node], d = deg[node], end = st + d;
    float a0 = 0.f, a1 = 0.f, b0 = 0.f, b1 = 0.f;
    float c0 = 0.f, c1 = 0.f, d0 = 0.f, d1 = 0.f;
    int e = st;
    for (; e + 3 < end; e += 4) {
        int s0 = srclist[e], s1 = srclist[e + 1], s2 = srclist[e + 2], s3 = srclist[e + 3];
        unsigned v0 = *(const unsigned*)(xb + (size_t)s0 * 128 + lane * 2);
        unsigned v1 = *(const unsigned*)(xb + (size_t)s1 * 128 + lane * 2);
        unsigned v2 = *(const unsigned*)(xb + (size_t)s2 * 128 + lane * 2);
        unsigned v3 = *(const unsigned*)(xb + (size_t)s3 * 128 + lane * 2);
        a0 += bfu_lo(v0); a1 += bfu_hi(v0);
        b0 += bfu_lo(v1); b1 += bfu_hi(v1);
        c0 += bfu_lo(v2); c1 += bfu_hi(v2);
        d0 += bfu_lo(v3); d1 += bfu_hi(v3);
    }
    for (; e < end; ++e) {
        unsigned v0 = *(const unsigned*)(xb + (size_t)srclist[e] * 128 + lane * 2);
        a0 += bfu_lo(v0); a1 += bfu_hi(v0);
    }
    float inv = 1.f / fmaxf((float)d, 1.f);
    ushort2 o = make_ushort2(f2bf(((a0 + b0) + (c0 + d0)) * inv),
                             f2bf(((a1 + b1) + (c1 + d1)) * inv));
    *(ushort2*)(acat + (size_t)node * 256 + lane * 2) = o;
}

__global__ void agg2_kernel(const unsigned short* __restrict__ h1, const int* __restrict__ srclist,
                            const int* __restrict__ offs, const int* __restrict__ deg,
                            unsigned short* __restrict__ acat, int n) {
    int gid = blockIdx.x * blockDim.x + threadIdx.x;
    int node = gid >> 6, lane = gid & 63;
    if (node >= n) return;
    int st = offs[node], d = deg[node], end = st + d;
    float a0 = 0, a1 = 0, a2 = 0, a3 = 0, b0 = 0, b1 = 0, b2 = 0, b3 = 0;
    float c0 = 0, c1 = 0, c2 = 0, c3 = 0, e0 = 0, e1 = 0, e2 = 0, e3 = 0;
    int e = st;
    for (; e + 3 < end; e += 4) {
        int s0 = srclist[e], s1 = srclist[e + 1], s2 = srclist[e + 2], s3 = srclist[e + 3];
        uint2 v0 = *(const uint2*)(h1 + (size_t)s0 * 256 + lane * 4);
        uint2 v1 = *(const uint2*)(h1 + (size_t)s1 * 256 + lane * 4);
        uint2 v2 = *(const uint2*)(h1 + (size_t)s2 * 256 + lane * 4);
        uint2 v3 = *(const uint2*)(h1 + (size_t)s3 * 256 + lane * 4);
        a0 += bfu_lo(v0.x); a1 += bfu_hi(v0.x); a2 += bfu_lo(v0.y); a3 += bfu_hi(v0.y);
        b0 += bfu_lo(v1.x); b1 += bfu_hi(v1.x); b2 += bfu_lo(v1.y); b3 += bfu_hi(v1.y);
        c0 += bfu_lo(v2.x); c1 += bfu_hi(v2.x); c2 += bfu_lo(v2.y); c3 += bfu_hi(v2.y);
        e0 += bfu_lo(v3.x); e1 += bfu_hi(v3.x); e2 += bfu_lo(v3.y); e3 += bfu_hi(v3.y);
    }
    for (; e < end; ++e) {
        uint2 v0 = *(const uint2*)(h1 + (size_t)srclist[e] * 256 + lane * 4);
        a0 += bfu_lo(v0.x); a1 += bfu_hi(v0.x); a2 += bfu_lo(v0.y); a3 += bfu_hi(v0.y);
    }
    float inv = 1.f / fmaxf((float)d, 1.f);
    ushort4 o = make_ushort4(f2bf(((a0 + b0) + (c0 + e0)) * inv),
                             f2bf(((a1 + b1) + (c1 + e1)) * inv),
                             f2bf(((a2 + b2) + (c2 + e2)) * inv),
                             f2bf(((a3 + b3) + (c3 + e3)) * inv));
    *(ushort4*)(acat + (size_t)node * 512 + lane * 4) = o;
}

// ---------------- MFMA GEMM (unchanged; see R1 notes for layout proofs) ----------------
template <int K>
__global__ __launch_bounds__(256) void mfma_gemm_kernel(
        const bf16_t* __restrict__ A, const bf16_t* __restrict__ Bt,
        const float* __restrict__ bias,
        unsigned short* __restrict__ H1, unsigned short* __restrict__ H2, int M) {
    int t = threadIdx.x;
    int wave = t >> 6, lane = t & 63;
    int quad = lane >> 4, l16 = lane & 15;
    int row0 = blockIdx.x * 64;
    int n0 = wave * 64;

    f32x4 acc[4][4];
#pragma unroll
    for (int i = 0; i < 4; ++i)
#pragma unroll
        for (int j = 0; j < 4; ++j) acc[i][j] = (f32x4)(0.f);

    const bf16_t* Ap = A + (size_t)(row0 + l16) * K + quad * 8;
    const bf16_t* Bp = Bt + (size_t)(n0 + l16) * K + quad * 8;

#pragma unroll 4
    for (int k0 = 0; k0 < K; k0 += 32) {
        bf16x8 af[4], bf[4];
#pragma unroll
        for (int mi = 0; mi < 4; ++mi)
            af[mi] = *(const bf16x8*)(Ap + (size_t)mi * 16 * K + k0);
#pragma unroll
        for (int ni = 0; ni < 4; ++ni)
            bf[ni] = *(const bf16x8*)(Bp + (size_t)ni * 16 * K + k0);
#pragma unroll
        for (int mi = 0; mi < 4; ++mi)
#pragma unroll
            for (int ni = 0; ni < 4; ++ni)
                acc[mi][ni] = __builtin_amdgcn_mfma_f32_16x16x32_bf16(af[mi], bf[ni], acc[mi][ni], 0, 0, 0);
    }

    float bv[4];
#pragma unroll
    for (int ni = 0; ni < 4; ++ni) bv[ni] = bias[n0 + ni * 16 + l16];

#pragma unroll
    for (int mi = 0; mi < 4; ++mi) {
#pragma unroll
        for (int r = 0; r < 4; ++r) {
            int row = row0 + mi * 16 + quad * 4 + r;
            if (row < M) {
#pragma unroll
                for (int ni = 0; ni < 4; ++ni) {
                    int col = n0 + ni * 16 + l16;
                    unsigned short hv = f2bf(fmaxf(acc[mi][ni][r] + bv[ni], 0.f));
                    H1[(size_t)row * 256 + col] = hv;
                    if (H2) H2[(size_t)row * 512 + 256 + col] = hv;
                }
            }
        }
    }
}

// ---------------- segmented mean pool ----------------
__global__ void pool_kernel(const unsigned short* __restrict__ h2, const int* __restrict__ batch,
                            float* __restrict__ g, float* __restrict__ cnt, int n) {
    int col = threadIdx.x;
    int row0 = blockIdx.x * 256;
    float acc = 0.f;
    int cur = -1, seglen = 0;
    for (int r = 0; r < 256; ++r) {
        int row = row0 + r;
        if (row >= n) break;
        int b = batch[row];
        if (b != cur) {
            if (cur >= 0) {
                atomicAdd(&g[cur * 256 + col], acc);
                if (col == 0) atomicAdd(&cnt[cur], (float)seglen);
            }
            acc = 0.f; cur = b; seglen = 0;
        }
        union { unsigned i; float f; } u;
        u.i = ((unsigned)h2[(size_t)row * 256 + col]) << 16;
        acc += u.f;
        seglen++;
    }
    if (cur >= 0) {
        atomicAdd(&g[cur * 256 + col], acc);
        if (col == 0) atomicAdd(&cnt[cur], (float)seglen);
    }
}

// ---------------- classifier ----------------
__global__ void final_kernel(const float* __restrict__ g, const float* __restrict__ cnt,
                             const float* __restrict__ fcW, const float* __restrict__ fcb,
                             float* __restrict__ out) {
    int t = threadIdx.x;
    for (int o = t; o < NGRAPH * NCLS; o += 256) {
        int gi = o >> 4, c = o & 15;
        float inv = 1.f / fmaxf(cnt[gi], 1.f);
        float dot = 0.f;
        for (int k = 0; k < 256; ++k) dot += g[gi * 256 + k] * fcW[k * 16 + c];
        out[o] = dot * inv + fcb[c];
    }
}

extern "C" void kernel_launch(void* const* d_in, const int* in_sizes, int n_in, void* d_out,
                              int out_size, void* d_ws, size_t ws_size, hipStream_t stream) {
    const float* x   = (const float*)d_in[0];
    const int* edge  = (const int*)d_in[1];
    const int* batch = (const int*)d_in[2];
    const float* W1l = (const float*)d_in[3];
    const float* b1  = (const float*)d_in[4];
    const float* W1r = (const float*)d_in[5];
    const float* W2l = (const float*)d_in[6];
    const float* b2  = (const float*)d_in[7];
    const float* W2r = (const float*)d_in[8];
    const float* fcW = (const float*)d_in[9];
    const float* fcb = (const float*)d_in[10];
    float* out = (float*)d_out;

    const int n = in_sizes[0] / INDIM;   // 100000
    const int E = in_sizes[1] / 2;       // 1600000
    const int* src = edge;
    const int* dst = edge + E;
    const int nbuck = (n + 255) >> 8;    // 391

    char* ws = (char*)d_ws;
    size_t off = 0;
    auto alloc = [&](size_t bytes) {
        size_t p = off;
        off = (off + bytes + 511) & ~(size_t)511;
        return p;
    };
    size_t offs_o    = alloc((size_t)n * 4);
    size_t deg_o     = alloc((size_t)n * 4);         // zeroed
    size_t cnt_o     = alloc(64 * 4);                // zeroed
    size_t g_o       = alloc(64 * 256 * 4);          // zeroed
    size_t zero_end  = off;
    size_t bsum_o    = alloc(1024 * 4);
    size_t gcur_o    = alloc(512 * 4);
    size_t srclist_o = alloc((size_t)E * 4);
    size_t bt1_o     = alloc(256 * 256 * 2);
    size_t bt2_o     = alloc(256 * 512 * 2);
    size_t acat2_o   = alloc((size_t)n * 512 * 2);   // first n*128*2 doubles as xb16
    size_t acat1_o   = alloc((size_t)n * 256 * 2);
    size_t h1_o      = alloc((size_t)n * 256 * 2);   // tmp (CSR build) -> h1b -> h2b

    int*   offs    = (int*)(ws + offs_o);
    int*   deg     = (int*)(ws + deg_o);
    float* cnt     = (float*)(ws + cnt_o);
    float* g       = (float*)(ws + g_o);
    int*   bsum    = (int*)(ws + bsum_o);
    int*   gcur    = (int*)(ws + gcur_o);
    int*   srclist = (int*)(ws + srclist_o);
    unsigned short* Bt1   = (unsigned short*)(ws + bt1_o);
    unsigned short* Bt2   = (unsigned short*)(ws + bt2_o);
    unsigned short* acat2 = (unsigned short*)(ws + acat2_o);
    unsigned short* xb16  = (unsigned short*)(ws + acat2_o);
    unsigned short* acat1 = (unsigned short*)(ws + acat1_o);
    unsigned*       tmp   = (unsigned*)(ws + h1_o);    // alias: dead before gemm1 writes h1b
    unsigned short* h1b   = (unsigned short*)(ws + h1_o);
    unsigned short* h2b   = (unsigned short*)(ws + h1_o);

    hipMemsetAsync(ws + deg_o, 0, zero_end - deg_o, stream);

    int eb = (E + 255) / 256;
    int nb = (n + 255) / 256;  // 391
    hist_kernel<<<eb, 256, 0, stream>>>(dst, deg, E);
    scan1_kernel<<<nb, 256, 0, stream>>>(deg, bsum, n);
    scan2_kernel<<<1, 1024, 0, stream>>>(bsum, nb);
    scan3_kernel<<<nb, 256, 0, stream>>>(deg, bsum, offs, n);
    initcur_kernel<<<(nbuck + 255) / 256, 256, 0, stream>>>(offs, gcur, nbuck);
    binA_kernel<<<(E + CHUNK - 1) / CHUNK, 256, 0, stream>>>(src, dst, gcur, tmp, E, nbuck);
    binB_kernel<<<nbuck, 256, 0, stream>>>(tmp, offs, srclist, E, n);

    cast_x_kernel<<<(n * INDIM / 4 + 255) / 256, 256, 0, stream>>>(x, xb16, acat1, n * INDIM / 4);
    wcast1_kernel<<<256, 256, 0, stream>>>(W1l, W1r, Bt1);
    wcast2_kernel<<<512, 256, 0, stream>>>(W2l, W2r, Bt2);

    int aggb = (n * 64 + 255) / 256;
    int gemmb = (n + 63) / 64;

    agg1_kernel<<<aggb, 256, 0, stream>>>(xb16, srclist, offs, deg, acat1, n);
    mfma_gemm_kernel<256><<<gemmb, 256, 0, stream>>>(
        (const bf16_t*)acat1, (const bf16_t*)Bt1, b1, h1b, acat2, n);
    agg2_kernel<<<aggb, 256, 0, stream>>>(h1b, srclist, offs, deg, acat2, n);
    mfma_gemm_kernel<512><<<gemmb, 256, 0, stream>>>(
        (const bf16_t*)acat2, (const bf16_t*)Bt2, b2, h2b, (unsigned short*)nullptr, n);

    pool_kernel<<<nb, 256, 0, stream>>>(h2b, batch, g, cnt, n);
    final_kernel<<<1, 256, 0, stream>>>(g, cnt, fcW, fcb, out);
}